// Round 12
// baseline (524.041 us; speedup 1.0000x reference)
//
#include <hip/hip_runtime.h>
#include <cstddef>

#define NPIX 16384
#define T_ 6

typedef __attribute__((ext_vector_type(8))) short bf16x8;
typedef __attribute__((ext_vector_type(4))) float f32x4;

__device__ __forceinline__ float leakyf(float x){ return x >= 0.f ? x : 0.2f*x; }
__device__ __forceinline__ float sigmf(float x){ return 1.f/(1.f+__expf(-x)); }
__device__ __forceinline__ short f2bf(float f){
    unsigned u = __float_as_uint(f);
    u += 0x7fffu + ((u>>16)&1u);
    return (short)(u>>16);
}
__device__ __forceinline__ float bf2f(short s){
    return __uint_as_float(((unsigned)(unsigned short)s)<<16);
}
__device__ __forceinline__ f32x4 MFMA(bf16x8 a, bf16x8 b, f32x4 c){
    return __builtin_amdgcn_mfma_f32_16x16x32_bf16(a, b, c, 0, 0, 0);
}

// ---- prep: weights -> bf16 [tap][oc][ic] (+ stem im2col [oc][64k]) ----
// wA_i2h [9][192][64] | wA_f1 [50][32][64] | wA_flow [25][32][32] | wA_ret [26][192][32] | wA_stem [384][64]
__global__ __launch_bounds__(256) void prep_w(const float* __restrict__ wi2h,
        const float* __restrict__ wf1i, const float* __restrict__ wf1h,
        const float* __restrict__ wfl, const float* __restrict__ wrt,
        const float* __restrict__ wst, short* __restrict__ dst){
    int idx = blockIdx.x*256 + threadIdx.x;
    float v;
    if(idx < 110592){
        int kk = idx/12288, r = idx%12288, oc = r>>6, ic = r&63;
        v = wi2h[((size_t)(oc*64+ic))*9 + kk];
    } else if(idx < 212992){
        int j = idx-110592; int tap = j>>11, r = j&2047, oc = r>>6, ic = r&63;
        int inp = tap/25, q = tap%25;
        const float* s = inp ? wf1h : wf1i;
        v = s[((size_t)(oc*64+ic))*25 + q];
    } else if(idx < 238592){
        int j = idx-212992; int q = j>>10, r = j&1023, oc = r>>5, ic = r&31;
        v = (oc < 26) ? wfl[((size_t)(oc*32+ic))*25 + q] : 0.f;
    } else if(idx < 398336){
        int j = idx-238592; int s_ = j/6144, r = j%6144, oc = r>>5, c = r&31;
        v = wrt[(size_t)oc*832 + s_*32 + c];
    } else {
        int j = idx-398336; int oc = j>>6, k = j&63;
        if(k < 54){ int ic = k/9, kk = k%9; v = wst[((size_t)(oc*6+ic))*9 + kk]; }
        else v = 0.f;
    }
    dst[idx] = f2bf(v);
}

// ---- stem MFMA: 3x3 s2 p1, 6->384, K=64(54), oc split across 2 blocks ----
__global__ __launch_bounds__(256) void stem_mfma(const float* __restrict__ x,
        const short* __restrict__ wS, const float* __restrict__ bias, short* __restrict__ ys_cl){
    __shared__ float xh[6*17*18];
    int bx = blockIdx.x;
    int ohalf = bx & 1, tile = (bx>>1) & 255, b = bx>>9;
    int ty0 = (tile>>4)*8, tx0 = (tile&15)*8;
    int tid = threadIdx.x, wid = tid>>6, lane = tid&63, lr = lane&15, lg = lane>>4;
    int iy0 = ty0*2-1, ix0 = tx0*2-1;
    for(int i=tid; i<1734; i+=256){
        int ic = i/289, r = i%289, hy = r/17, hx = r%17;
        int iy = iy0+hy, ix = ix0+hx;
        float v = 0.f;
        if((unsigned)iy<256u && (unsigned)ix<256u) v = x[((size_t)b*6+ic)*65536 + iy*256 + ix];
        xh[(ic*17+hy)*18+hx] = v;
    }
    __syncthreads();
    int pxl = wid*16 + lr;
    int ry = (pxl>>3)*2, rx = (pxl&7)*2;
    bf16x8 a[2];
    #pragma unroll
    for(int cg=0; cg<2; ++cg){
        #pragma unroll
        for(int e=0; e<8; ++e){
            int k = cg*32 + lg*8 + e;
            float v = 0.f;
            if(k < 54){
                int ic = k/9, t9 = k%9, ky = t9/3, kx = t9%3;
                v = xh[(ic*17 + ry+ky)*18 + rx+kx];
            }
            a[cg][e] = f2bf(v);
        }
    }
    short* yb = ys_cl + (size_t)b*NPIX*384;
    #pragma unroll
    for(int nj=0; nj<12; ++nj){
        int oc = (ohalf*12 + nj)*16 + lr;
        f32x4 acc = {};
        #pragma unroll
        for(int cg=0; cg<2; ++cg){
            bf16x8 bb = *(const bf16x8*)&wS[(size_t)oc*64 + cg*32 + lg*8];
            acc = MFMA(a[cg], bb, acc);
        }
        float bvs = bias[oc];
        #pragma unroll
        for(int r=0; r<4; ++r){
            int pxr = wid*16 + lg*4 + r;
            int pix = (ty0 + (pxr>>3))*128 + tx0 + (pxr&7);
            yb[(size_t)pix*384 + oc] = f2bf(leakyf(acc[r]+bvs));
        }
    }
}

// ---- fused pre-loop: 8x32 tiles (M=256), 512 thr; i2h (3x3->192) + i2f partial (5x5->32) ----
__global__ __launch_bounds__(512) void ih_if_mfma(const short* __restrict__ ys_cl,
        const short* __restrict__ wI, const float* __restrict__ bI,
        const short* __restrict__ wF,
        float* __restrict__ i2h_all, float* __restrict__ f1i_all){
    __shared__ short xt[432*72];            // halo 12 rows x 36 px, 64ch rows (stride 72) = 62 KB
    int bx = blockIdx.x;
    int tile = bx & 63; int r_ = bx >> 6; int t = r_ % 6; int b = r_ / 6;
    int ty0 = (tile>>2)*8, tx0 = (tile&3)*32;
    int tid = threadIdx.x, wid = tid>>6, lane = tid&63, lr = lane&15, lg = lane>>4;
    int mw = wid>>2, nw = wid&3;
    const short* xb = ys_cl + (size_t)b*NPIX*384 + t*64;
    for(int i=tid; i<3456; i+=512){
        int pix = i>>3, c8 = i&7;
        int hy = pix/36, hx = pix - hy*36;
        int py = ty0 - 2 + hy, px = tx0 - 2 + hx;
        bf16x8 v = {};
        if((unsigned)py < 128u && (unsigned)px < 128u)
            v = *(const bf16x8*)&xb[((size_t)py*128 + px)*384 + c8*8];
        *(bf16x8*)&xt[pix*72 + c8*8] = v;
    }
    __syncthreads();
    // ---- i2h: 3x3, this wave: rows mw*4+{0..3}, oc nw*48+{0..47} ----
    f32x4 accI[4][2][3] = {};
    for(int kk=0; kk<9; ++kk){
        int ky = kk/3, kx = kk - ky*3;
        #pragma unroll
        for(int cg=0; cg<2; ++cg){
            bf16x8 bv[3];
            #pragma unroll
            for(int ni=0; ni<3; ++ni)
                bv[ni] = *(const bf16x8*)&wI[((size_t)kk*192 + nw*48 + ni*16 + lr)*64 + cg*32 + lg*8];
            #pragma unroll
            for(int ri=0; ri<4; ++ri){
                int r2 = mw*4 + ri;
                bf16x8 av[2];
                #pragma unroll
                for(int mi=0; mi<2; ++mi){
                    int hp = (r2 + ky + 1)*36 + mi*16 + lr + kx + 1;
                    av[mi] = *(const bf16x8*)&xt[hp*72 + cg*32 + lg*8];
                }
                #pragma unroll
                for(int mi=0; mi<2; ++mi)
                  #pragma unroll
                  for(int ni=0; ni<3; ++ni)
                    accI[ri][mi][ni] = MFMA(av[mi], bv[ni], accI[ri][mi][ni]);
            }
        }
    }
    float* oI = i2h_all + ((size_t)t*2 + b)*192*NPIX;
    #pragma unroll
    for(int ri=0; ri<4; ++ri){
        int py = ty0 + mw*4 + ri;
        #pragma unroll
        for(int mi=0; mi<2; ++mi){
            int px = tx0 + mi*16 + lg*4;
            #pragma unroll
            for(int ni=0; ni<3; ++ni){
                int oc = nw*48 + ni*16 + lr;
                float bvs = bI[oc];
                f32x4 r = accI[ri][mi][ni];
                f32x4 st; st[0]=r[0]+bvs; st[1]=r[1]+bvs; st[2]=r[2]+bvs; st[3]=r[3]+bvs;
                *(f32x4*)&oI[(size_t)oc*NPIX + py*128 + px] = st;
            }
        }
    }
    // ---- i2f: 5x5, partial; this wave: rows mw*4+{0..3}, px-half nw>>1, oc (nw&1)*16+{0..15} ----
    f32x4 accF[4] = {};
    int mif = nw>>1, jF = (nw&1)*16 + lr;
    for(int q=0; q<25; ++q){
        int ky = q/5, kx = q - ky*5;
        #pragma unroll
        for(int cg=0; cg<2; ++cg){
            bf16x8 bb = *(const bf16x8*)&wF[((size_t)q*32 + (nw&1)*16 + lr)*64 + cg*32 + lg*8];
            #pragma unroll
            for(int ri=0; ri<4; ++ri){
                int hp = (mw*4 + ri + ky)*36 + mif*16 + lr + kx;
                bf16x8 av = *(const bf16x8*)&xt[hp*72 + cg*32 + lg*8];
                accF[ri] = MFMA(av, bb, accF[ri]);
            }
        }
    }
    float* oF = f1i_all + ((size_t)t*2 + b)*32*NPIX;
    #pragma unroll
    for(int ri=0; ri<4; ++ri){
        int py = ty0 + mw*4 + ri;
        int px = tx0 + mif*16 + lg*4;
        *(f32x4*)&oF[(size_t)jF*NPIX + py*128 + px] = accF[ri];
    }
}

// ---- f1h (per step): h2f(5x5 on h_cl) + i2f partial + leaky -> f1_cl bf16 ----
__global__ __launch_bounds__(256) void f1h_mfma(const short* __restrict__ h_cl,
        const short* __restrict__ wF, const float* __restrict__ f1i_all, int t,
        const float* __restrict__ bi, const float* __restrict__ bh,
        short* __restrict__ f1_cl){
    __shared__ short xt[144*72];
    int bx = blockIdx.x;
    int tile = bx & 255, b = bx>>8;
    int ty0 = (tile>>4)*8, tx0 = (tile&15)*8;
    int tid = threadIdx.x, wid = tid>>6, lane = tid&63, lr = lane&15, lg = lane>>4;
    int mw = wid>>1, nw = wid&1;
    const short* xb = h_cl + (size_t)b*NPIX*64;
    for(int i=tid; i<1152; i+=256){
        int pix = i>>3, c8 = i&7;
        int hy = pix/12, hx = pix - hy*12;
        int py = ty0 - 2 + hy, px = tx0 - 2 + hx;
        bf16x8 v = {};
        if((unsigned)py < 128u && (unsigned)px < 128u)
            v = *(const bf16x8*)&xb[((size_t)py*128 + px)*64 + c8*8];
        *(bf16x8*)&xt[pix*72 + c8*8] = v;
    }
    __syncthreads();
    f32x4 acc[2] = {};
    for(int q=0; q<25; ++q){
        int ky = q/5, kx = q - ky*5;
        #pragma unroll
        for(int cg=0; cg<2; ++cg){
            bf16x8 av[2];
            #pragma unroll
            for(int mi=0; mi<2; ++mi){
                int m = mw*32 + mi*16 + lr;
                int hp = ((m>>3)+ky)*12 + (m&7)+kx;
                av[mi] = *(const bf16x8*)&xt[hp*72 + cg*32 + lg*8];
            }
            bf16x8 bb = *(const bf16x8*)&wF[((size_t)(25+q)*32 + nw*16 + lr)*64 + cg*32 + lg*8];
            #pragma unroll
            for(int mi=0; mi<2; ++mi) acc[mi] = MFMA(av[mi], bb, acc[mi]);
        }
    }
    int j = nw*16 + lr;
    float bvs = bi[j] + bh[j];
    const float* pF = f1i_all + ((size_t)t*2 + b)*32*NPIX;
    __syncthreads();                        // reuse xt as [64px][40] transpose
    #pragma unroll
    for(int mi=0; mi<2; ++mi){
        int m0 = mw*32 + mi*16 + lg*4;
        int py = ty0 + (m0>>3), px = tx0 + (m0&7);
        f32x4 p = *(const f32x4*)&pF[(size_t)j*NPIX + py*128 + px];
        #pragma unroll
        for(int r=0; r<4; ++r) xt[(m0+r)*40 + j] = f2bf(leakyf(acc[mi][r] + p[r] + bvs));
    }
    __syncthreads();
    {
        int px = tid>>2, c8 = tid&3;
        int pix = (ty0 + (px>>3))*128 + tx0 + (px&7);
        *(bf16x8*)&f1_cl[((size_t)b*NPIX + pix)*32 + c8*8] = *(const bf16x8*)&xt[px*40 + c8*8];
    }
}

// ---- flow: 5x5 p2, 32->26(pad 32), 256 thr, B direct from global ----
__global__ __launch_bounds__(256) void flow_mfma(const short* __restrict__ f1_cl,
        const short* __restrict__ wA, const float* __restrict__ bias, float* __restrict__ flows){
    __shared__ short xt[144*40];
    int bx = blockIdx.x;
    int tile = bx & 255, b = bx>>8;
    int ty0 = (tile>>4)*8, tx0 = (tile&15)*8;
    int tid = threadIdx.x, wid = tid>>6, lane = tid&63, lr = lane&15, lg = lane>>4;
    int mw = wid>>1, nw = wid&1;
    f32x4 acc[2] = {};
    const short* xb = f1_cl + (size_t)b*NPIX*32;
    for(int i=tid; i<576; i+=256){
        int pix = i>>2, c8 = i&3;
        int hy = pix/12, hx = pix - hy*12;
        int py = ty0 - 2 + hy, px = tx0 - 2 + hx;
        bf16x8 v = {};
        if((unsigned)py < 128u && (unsigned)px < 128u)
            v = *(const bf16x8*)&xb[((size_t)py*128 + px)*32 + c8*8];
        *(bf16x8*)&xt[pix*40 + c8*8] = v;
    }
    __syncthreads();
    for(int ky=0; ky<5; ++ky){
        #pragma unroll
        for(int kx=0; kx<5; ++kx){
            bf16x8 av[2];
            #pragma unroll
            for(int mi=0; mi<2; ++mi){
                int m = mw*32 + mi*16 + lr;
                int hp = ((m>>3)+ky)*12 + (m&7) + kx;
                av[mi] = *(const bf16x8*)&xt[hp*40 + lg*8];
            }
            bf16x8 bb = *(const bf16x8*)&wA[((size_t)((ky*5+kx)*32) + nw*16 + lr)*32 + lg*8];
            #pragma unroll
            for(int mi=0; mi<2; ++mi) acc[mi] = MFMA(av[mi], bb, acc[mi]);
        }
    }
    int j = nw*16 + lr;
    if(j < 26){
        float bvs = bias[j];
        #pragma unroll
        for(int mi=0; mi<2; ++mi){
            int m0 = mw*32 + mi*16 + lg*4;
            int py = ty0 + (m0>>3), px = tx0 + (m0&7);
            f32x4 r = acc[mi];
            f32x4 st; st[0]=r[0]+bvs; st[1]=r[1]+bvs; st[2]=r[2]+bvs; st[3]=r[3]+bvs;
            *(f32x4*)&flows[((size_t)b*26 + j)*NPIX + py*128 + px] = st;
        }
    }
}

// ---- warpret: producer/consumer waves; LDS dbuf gather + GEMM + fused GRU ----
__device__ __forceinline__ void calc_corners(const float* __restrict__ s_sx,
        const float* __restrict__ s_sy, int l, int mypx,
        int& i00, int& i10, int& i01, int& i11,
        float& w00, float& w10, float& w01, float& w11){
    float sx = s_sx[l*64+mypx], sy = s_sy[l*64+mypx];
    float x0f = floorf(sx), y0f = floorf(sy);
    int x0 = (int)x0f, y0 = (int)y0f;
    float wx1 = sx-x0f, wy1 = sy-y0f, wx0 = 1.f-wx1, wy0 = 1.f-wy1;
    bool vx0 = (unsigned)x0<128u, vx1 = (unsigned)(x0+1)<128u;
    bool vy0 = (unsigned)y0<128u, vy1 = (unsigned)(y0+1)<128u;
    w00 = (vx0&&vy0)? wx0*wy0 : 0.f;
    w10 = (vx1&&vy0)? wx1*wy0 : 0.f;
    w01 = (vx0&&vy1)? wx0*wy1 : 0.f;
    w11 = (vx1&&vy1)? wx1*wy1 : 0.f;
    int xc0 = max(0,min(127,x0)), xc1 = max(0,min(127,x0+1));
    int yc0 = max(0,min(127,y0)), yc1 = max(0,min(127,y0+1));
    i00 = yc0*128+xc0; i10 = yc0*128+xc1; i01 = yc1*128+xc0; i11 = yc1*128+xc1;
}

__global__ __launch_bounds__(512,2) void warpret_mfma(
        const float* __restrict__ hprev_f32, int hstride,
        const short* __restrict__ h_in,
        const float* __restrict__ flows,
        const short* __restrict__ wret, const float* __restrict__ b_ret,
        const float* __restrict__ ib_f32, float* __restrict__ out,
        short* __restrict__ h_out, int t){
    __shared__ float s_sx[832], s_sy[832];
    __shared__ short At[2][64*40];
    __shared__ short Bt[2][192*40];
    int bx = blockIdx.x;
    int half = bx & 1, row = (bx>>1) & 127, b = bx >> 8;
    int pxbase = half*64;
    int tid = threadIdx.x, wid = tid>>6, lane = tid&63, lr = lane&15, lg = lane>>4;
    bool producer = tid >= 256;
    int stid = tid & 255;
    const short* hc = h_in + (size_t)b*NPIX*64;
    f32x4 acc[12] = {};
    for(int i=tid; i<832; i+=512){
        int l = i>>6, px = i&63;
        float u = flows[((size_t)b*26 + 2*l)*NPIX + row*128 + pxbase + px];
        float v = flows[((size_t)b*26 + 2*l+1)*NPIX + row*128 + pxbase + px];
        s_sx[i] = (float)(pxbase+px) - u;
        s_sy[i] = (float)row - v;
    }
    __syncthreads();

    int spx = stid & 63;
    int sch = stid >> 6;
    int brow = stid >> 2, bc4 = stid & 3;

    int i00=0,i10=0,i01=0,i11=0; float w00=0,w10=0,w01=0,w11=0;
    if(producer){
        calc_corners(s_sx, s_sy, 0, spx, i00,i10,i01,i11, w00,w10,w01,w11);
        int cb = sch*8;
        bf16x8 a00 = *(const bf16x8*)&hc[(size_t)i00*64 + cb];
        bf16x8 a10 = *(const bf16x8*)&hc[(size_t)i10*64 + cb];
        bf16x8 a01 = *(const bf16x8*)&hc[(size_t)i01*64 + cb];
        bf16x8 a11 = *(const bf16x8*)&hc[(size_t)i11*64 + cb];
        bf16x8 av;
        #pragma unroll
        for(int e=0; e<8; ++e)
            av[e] = f2bf(bf2f(a00[e])*w00 + bf2f(a10[e])*w10 +
                         bf2f(a01[e])*w01 + bf2f(a11[e])*w11);
        *(bf16x8*)&At[0][spx*40 + sch*8] = av;
        #pragma unroll
        for(int k=0; k<3; ++k)
            *(bf16x8*)&Bt[0][(brow + k*64)*40 + bc4*8] =
                *(const bf16x8*)&wret[((size_t)0*192 + brow + k*64)*32 + bc4*8];
    }
    __syncthreads();

    for(int s=0; s<26; ++s){
        int cur = s & 1, nxt = cur ^ 1;
        if(producer){
            if(s < 25){
                int sp = s+1, sl = sp>>1, scg = sp&1;
                if(scg == 0)
                    calc_corners(s_sx, s_sy, sl, spx, i00,i10,i01,i11, w00,w10,w01,w11);
                int cb = scg*32 + sch*8;
                bf16x8 p00 = *(const bf16x8*)&hc[(size_t)i00*64 + cb];
                bf16x8 p10 = *(const bf16x8*)&hc[(size_t)i10*64 + cb];
                bf16x8 p01 = *(const bf16x8*)&hc[(size_t)i01*64 + cb];
                bf16x8 p11 = *(const bf16x8*)&hc[(size_t)i11*64 + cb];
                bf16x8 q0 = *(const bf16x8*)&wret[((size_t)sp*192 + brow      )*32 + bc4*8];
                bf16x8 q1 = *(const bf16x8*)&wret[((size_t)sp*192 + brow +  64)*32 + bc4*8];
                bf16x8 q2 = *(const bf16x8*)&wret[((size_t)sp*192 + brow + 128)*32 + bc4*8];
                bf16x8 av;
                #pragma unroll
                for(int e=0; e<8; ++e)
                    av[e] = f2bf(bf2f(p00[e])*w00 + bf2f(p10[e])*w10 +
                                 bf2f(p01[e])*w01 + bf2f(p11[e])*w11);
                *(bf16x8*)&At[nxt][spx*40 + sch*8] = av;
                *(bf16x8*)&Bt[nxt][(brow      )*40 + bc4*8] = q0;
                *(bf16x8*)&Bt[nxt][(brow +  64)*40 + bc4*8] = q1;
                *(bf16x8*)&Bt[nxt][(brow + 128)*40 + bc4*8] = q2;
            }
        } else {
            bf16x8 a = *(const bf16x8*)&At[cur][(wid*16 + lr)*40 + lg*8];
            #pragma unroll
            for(int ni=0; ni<12; ++ni){
                bf16x8 bb = *(const bf16x8*)&Bt[cur][(ni*16 + lr)*40 + lg*8];
                acc[ni] = MFMA(a, bb, acc[ni]);
            }
        }
        __syncthreads();
    }

    short* Ht = &Bt[0][0];
    if(!producer){
        const float* ib  = ib_f32 + (size_t)b*192*NPIX + row*128 + pxbase;
        const float* hbf = hprev_f32 + (size_t)b*hstride + row*128 + pxbase;
        float* ob = out + (((size_t)b*T_ + t)*64)*NPIX + row*128 + pxbase;
        int px4 = wid*16 + lg*4;
        #pragma unroll
        for(int ni=0; ni<4; ++ni){
            int oc = ni*16 + lr;
            f32x4 ir = *(const f32x4*)&ib[(size_t)oc*NPIX + px4];
            f32x4 iu = *(const f32x4*)&ib[(size_t)(64+oc)*NPIX + px4];
            f32x4 im = *(const f32x4*)&ib[(size_t)(128+oc)*NPIX + px4];
            f32x4 hp = *(const f32x4*)&hbf[(size_t)oc*NPIX + px4];
            float br = b_ret[oc], bu = b_ret[64+oc], bm = b_ret[128+oc];
            f32x4 st;
            #pragma unroll
            for(int r=0; r<4; ++r){
                float hr = acc[ni][r] + br;
                float hu = acc[ni+4][r] + bu;
                float hm = acc[ni+8][r] + bm;
                float rg = sigmf(ir[r] + hr);
                float zg = sigmf(iu[r] + hu);
                float mg = leakyf(im[r] + rg*hm);
                st[r] = zg*hp[r] + (1.f-zg)*mg;
            }
            *(f32x4*)&ob[(size_t)oc*NPIX + px4] = st;
            #pragma unroll
            for(int r=0; r<4; ++r) Ht[(px4+r)*72 + oc] = f2bf(st[r]);
        }
    }
    __syncthreads();
    {
        int px = tid>>3, c8 = tid&7;   // 512 threads cover 64px x 8 chunks exactly
        short* ho = h_out + ((size_t)b*NPIX + row*128 + pxbase)*64;
        *(bf16x8*)&ho[(size_t)px*64 + c8*8] = *(const bf16x8*)&Ht[px*72 + c8*8];
    }
}

extern "C" void kernel_launch(void* const* d_in, const int* in_sizes, int n_in,
                              void* d_out, int out_size, void* d_ws, size_t ws_size,
                              hipStream_t stream) {
    const float* x      = (const float*)d_in[0];
    const float* w_stem = (const float*)d_in[1];
    const float* b_stem = (const float*)d_in[2];
    const float* w_i2h  = (const float*)d_in[3];
    const float* b_i2h  = (const float*)d_in[4];
    const float* w_i2f  = (const float*)d_in[5];
    const float* b_i2f  = (const float*)d_in[6];
    const float* w_h2f  = (const float*)d_in[7];
    const float* b_h2f  = (const float*)d_in[8];
    const float* w_flow = (const float*)d_in[9];
    const float* b_flow = (const float*)d_in[10];
    const float* w_ret  = (const float*)d_in[11];
    const float* b_ret  = (const float*)d_in[12];
    float* out = (float*)d_out;

    char* w = (char*)d_ws;
    float* h0_f32  = (float*)w;  w += (size_t)2*64*NPIX*4;
    float* i2h_all = (float*)w;  w += (size_t)6*2*192*NPIX*4;
    float* f1i_all = (float*)w;  w += (size_t)6*2*32*NPIX*4;
    float* flows   = (float*)w;  w += (size_t)2*26*NPIX*4;
    short* ys_cl   = (short*)w;  w += (size_t)2*NPIX*384*2;
    short* h_clA   = (short*)w;  w += (size_t)2*NPIX*64*2;
    short* h_clB   = (short*)w;  w += (size_t)2*NPIX*64*2;
    short* f1_cl   = (short*)w;  w += (size_t)2*NPIX*32*2;
    short* wAbase  = (short*)w;
    short* wA_i2h  = wAbase;
    short* wA_f1   = wAbase + 110592;
    short* wA_flow = wAbase + 212992;
    short* wA_ret  = wAbase + 238592;
    short* wA_stem = wAbase + 398336;

    prep_w<<<1652, 256, 0, stream>>>(w_i2h, w_i2f, w_h2f, w_flow, w_ret, w_stem, wAbase);
    hipMemsetAsync(h0_f32, 0, (size_t)2*64*NPIX*4, stream);
    hipMemsetAsync(h_clA, 0, (size_t)2*NPIX*64*2, stream);

    stem_mfma<<<1024, 256, 0, stream>>>(x, wA_stem, b_stem, ys_cl);
    ih_if_mfma<<<768, 512, 0, stream>>>(ys_cl, wA_i2h, b_i2h, wA_f1, i2h_all, f1i_all);

    for (int t = 0; t < T_; ++t) {
        const float* hprev = (t == 0) ? h0_f32 : out + (size_t)(t - 1) * 64 * NPIX;
        int hstride = (t == 0) ? 64 * NPIX : T_ * 64 * NPIX;
        short* h_in  = (t & 1) ? h_clB : h_clA;
        short* h_nxt = (t & 1) ? h_clA : h_clB;
        f1h_mfma<<<512, 256, 0, stream>>>(h_in, wA_f1, f1i_all, t, b_i2f, b_h2f, f1_cl);
        flow_mfma<<<512, 256, 0, stream>>>(f1_cl, wA_flow, b_flow, flows);
        warpret_mfma<<<512, 512, 0, stream>>>(hprev, hstride, h_in, flows,
                                              wA_ret, b_ret,
                                              i2h_all + ((size_t)t*2)*192*NPIX,
                                              out, h_nxt, t);
    }
}

// Round 13
// 497.290 us; speedup vs baseline: 1.0538x; 1.0538x over previous
//
#include <hip/hip_runtime.h>
#include <cstddef>

#define NPIX 16384
#define T_ 6

typedef __attribute__((ext_vector_type(8))) short bf16x8;
typedef __attribute__((ext_vector_type(4))) short bf16x4;
typedef __attribute__((ext_vector_type(4))) float f32x4;

__device__ __forceinline__ float leakyf(float x){ return x >= 0.f ? x : 0.2f*x; }
__device__ __forceinline__ float sigmf(float x){ return 1.f/(1.f+__expf(-x)); }
__device__ __forceinline__ short f2bf(float f){
    unsigned u = __float_as_uint(f);
    u += 0x7fffu + ((u>>16)&1u);
    return (short)(u>>16);
}
__device__ __forceinline__ float bf2f(short s){
    return __uint_as_float(((unsigned)(unsigned short)s)<<16);
}
__device__ __forceinline__ f32x4 MFMA(bf16x8 a, bf16x8 b, f32x4 c){
    return __builtin_amdgcn_mfma_f32_16x16x32_bf16(a, b, c, 0, 0, 0);
}

// ---- prep: weights -> bf16 [tap][oc][ic] (+ stem im2col [oc][64k]) ----
// wA_i2h [9][192][64] | wA_f1 [50][32][64] | wA_flow [25][32][32] | wA_ret [26][192][32] | wA_stem [384][64]
__global__ __launch_bounds__(256) void prep_w(const float* __restrict__ wi2h,
        const float* __restrict__ wf1i, const float* __restrict__ wf1h,
        const float* __restrict__ wfl, const float* __restrict__ wrt,
        const float* __restrict__ wst, short* __restrict__ dst){
    int idx = blockIdx.x*256 + threadIdx.x;
    float v;
    if(idx < 110592){
        int kk = idx/12288, r = idx%12288, oc = r>>6, ic = r&63;
        v = wi2h[((size_t)(oc*64+ic))*9 + kk];
    } else if(idx < 212992){
        int j = idx-110592; int tap = j>>11, r = j&2047, oc = r>>6, ic = r&63;
        int inp = tap/25, q = tap%25;
        const float* s = inp ? wf1h : wf1i;
        v = s[((size_t)(oc*64+ic))*25 + q];
    } else if(idx < 238592){
        int j = idx-212992; int q = j>>10, r = j&1023, oc = r>>5, ic = r&31;
        v = (oc < 26) ? wfl[((size_t)(oc*32+ic))*25 + q] : 0.f;
    } else if(idx < 398336){
        int j = idx-238592; int s_ = j/6144, r = j%6144, oc = r>>5, c = r&31;
        v = wrt[(size_t)oc*832 + s_*32 + c];
    } else {
        int j = idx-398336; int oc = j>>6, k = j&63;
        if(k < 54){ int ic = k/9, kk = k%9; v = wst[((size_t)(oc*6+ic))*9 + kk]; }
        else v = 0.f;
    }
    dst[idx] = f2bf(v);
}

// ---- stem MFMA: 3x3 s2 p1, 6->384, K=64(54), oc split across 2 blocks ----
__global__ __launch_bounds__(256) void stem_mfma(const float* __restrict__ x,
        const short* __restrict__ wS, const float* __restrict__ bias, short* __restrict__ ys_cl){
    __shared__ float xh[6*17*18];
    int bx = blockIdx.x;
    int ohalf = bx & 1, tile = (bx>>1) & 255, b = bx>>9;
    int ty0 = (tile>>4)*8, tx0 = (tile&15)*8;
    int tid = threadIdx.x, wid = tid>>6, lane = tid&63, lr = lane&15, lg = lane>>4;
    int iy0 = ty0*2-1, ix0 = tx0*2-1;
    for(int i=tid; i<1734; i+=256){
        int ic = i/289, r = i%289, hy = r/17, hx = r%17;
        int iy = iy0+hy, ix = ix0+hx;
        float v = 0.f;
        if((unsigned)iy<256u && (unsigned)ix<256u) v = x[((size_t)b*6+ic)*65536 + iy*256 + ix];
        xh[(ic*17+hy)*18+hx] = v;
    }
    __syncthreads();
    int pxl = wid*16 + lr;
    int ry = (pxl>>3)*2, rx = (pxl&7)*2;
    bf16x8 a[2];
    #pragma unroll
    for(int cg=0; cg<2; ++cg){
        #pragma unroll
        for(int e=0; e<8; ++e){
            int k = cg*32 + lg*8 + e;
            float v = 0.f;
            if(k < 54){
                int ic = k/9, t9 = k%9, ky = t9/3, kx = t9%3;
                v = xh[(ic*17 + ry+ky)*18 + rx+kx];
            }
            a[cg][e] = f2bf(v);
        }
    }
    short* yb = ys_cl + (size_t)b*NPIX*384;
    #pragma unroll
    for(int nj=0; nj<12; ++nj){
        int oc = (ohalf*12 + nj)*16 + lr;
        f32x4 acc = {};
        #pragma unroll
        for(int cg=0; cg<2; ++cg){
            bf16x8 bb = *(const bf16x8*)&wS[(size_t)oc*64 + cg*32 + lg*8];
            acc = MFMA(a[cg], bb, acc);
        }
        float bvs = bias[oc];
        #pragma unroll
        for(int r=0; r<4; ++r){
            int pxr = wid*16 + lg*4 + r;
            int pix = (ty0 + (pxr>>3))*128 + tx0 + (pxr&7);
            yb[(size_t)pix*384 + oc] = f2bf(leakyf(acc[r]+bvs));
        }
    }
}

// ---- fused pre-loop: 8x32 tiles (M=256), 512 thr; i2h (3x3->192, bf16 out) + i2f partial ----
__global__ __launch_bounds__(512) void ih_if_mfma(const short* __restrict__ ys_cl,
        const short* __restrict__ wI, const float* __restrict__ bI,
        const short* __restrict__ wF,
        short* __restrict__ i2h_all, float* __restrict__ f1i_all){
    __shared__ short xt[432*72];            // halo 12 rows x 36 px, 64ch rows (stride 72) = 62 KB
    int bx = blockIdx.x;
    int tile = bx & 63; int r_ = bx >> 6; int t = r_ % 6; int b = r_ / 6;
    int ty0 = (tile>>2)*8, tx0 = (tile&3)*32;
    int tid = threadIdx.x, wid = tid>>6, lane = tid&63, lr = lane&15, lg = lane>>4;
    int mw = wid>>2, nw = wid&3;
    const short* xb = ys_cl + (size_t)b*NPIX*384 + t*64;
    for(int i=tid; i<3456; i+=512){
        int pix = i>>3, c8 = i&7;
        int hy = pix/36, hx = pix - hy*36;
        int py = ty0 - 2 + hy, px = tx0 - 2 + hx;
        bf16x8 v = {};
        if((unsigned)py < 128u && (unsigned)px < 128u)
            v = *(const bf16x8*)&xb[((size_t)py*128 + px)*384 + c8*8];
        *(bf16x8*)&xt[pix*72 + c8*8] = v;
    }
    __syncthreads();
    // ---- i2h: 3x3, this wave: rows mw*4+{0..3}, oc nw*48+{0..47} ----
    f32x4 accI[4][2][3] = {};
    for(int kk=0; kk<9; ++kk){
        int ky = kk/3, kx = kk - ky*3;
        #pragma unroll
        for(int cg=0; cg<2; ++cg){
            bf16x8 bv[3];
            #pragma unroll
            for(int ni=0; ni<3; ++ni)
                bv[ni] = *(const bf16x8*)&wI[((size_t)kk*192 + nw*48 + ni*16 + lr)*64 + cg*32 + lg*8];
            #pragma unroll
            for(int ri=0; ri<4; ++ri){
                int r2 = mw*4 + ri;
                bf16x8 av[2];
                #pragma unroll
                for(int mi=0; mi<2; ++mi){
                    int hp = (r2 + ky + 1)*36 + mi*16 + lr + kx + 1;
                    av[mi] = *(const bf16x8*)&xt[hp*72 + cg*32 + lg*8];
                }
                #pragma unroll
                for(int mi=0; mi<2; ++mi)
                  #pragma unroll
                  for(int ni=0; ni<3; ++ni)
                    accI[ri][mi][ni] = MFMA(av[mi], bv[ni], accI[ri][mi][ni]);
            }
        }
    }
    short* oI = i2h_all + ((size_t)t*2 + b)*192*NPIX;
    #pragma unroll
    for(int ri=0; ri<4; ++ri){
        int py = ty0 + mw*4 + ri;
        #pragma unroll
        for(int mi=0; mi<2; ++mi){
            int px = tx0 + mi*16 + lg*4;
            #pragma unroll
            for(int ni=0; ni<3; ++ni){
                int oc = nw*48 + ni*16 + lr;
                float bvs = bI[oc];
                f32x4 r = accI[ri][mi][ni];
                bf16x4 st;
                st[0]=f2bf(r[0]+bvs); st[1]=f2bf(r[1]+bvs);
                st[2]=f2bf(r[2]+bvs); st[3]=f2bf(r[3]+bvs);
                *(bf16x4*)&oI[(size_t)oc*NPIX + py*128 + px] = st;
            }
        }
    }
    // ---- i2f: 5x5, partial; this wave: rows mw*4+{0..3}, px-half nw>>1, oc (nw&1)*16+{0..15} ----
    f32x4 accF[4] = {};
    int mif = nw>>1, jF = (nw&1)*16 + lr;
    for(int q=0; q<25; ++q){
        int ky = q/5, kx = q - ky*5;
        #pragma unroll
        for(int cg=0; cg<2; ++cg){
            bf16x8 bb = *(const bf16x8*)&wF[((size_t)q*32 + (nw&1)*16 + lr)*64 + cg*32 + lg*8];
            #pragma unroll
            for(int ri=0; ri<4; ++ri){
                int hp = (mw*4 + ri + ky)*36 + mif*16 + lr + kx;
                bf16x8 av = *(const bf16x8*)&xt[hp*72 + cg*32 + lg*8];
                accF[ri] = MFMA(av, bb, accF[ri]);
            }
        }
    }
    float* oF = f1i_all + ((size_t)t*2 + b)*32*NPIX;
    #pragma unroll
    for(int ri=0; ri<4; ++ri){
        int py = ty0 + mw*4 + ri;
        int px = tx0 + mif*16 + lg*4;
        *(f32x4*)&oF[(size_t)jF*NPIX + py*128 + px] = accF[ri];
    }
}

// ---- f1h (per step): h2f(5x5 on h_cl) + i2f partial + leaky -> f1_cl bf16 ----
__global__ __launch_bounds__(256) void f1h_mfma(const short* __restrict__ h_cl,
        const short* __restrict__ wF, const float* __restrict__ f1i_all, int t,
        const float* __restrict__ bi, const float* __restrict__ bh,
        short* __restrict__ f1_cl){
    __shared__ short xt[144*72];
    int bx = blockIdx.x;
    int tile = bx & 255, b = bx>>8;
    int ty0 = (tile>>4)*8, tx0 = (tile&15)*8;
    int tid = threadIdx.x, wid = tid>>6, lane = tid&63, lr = lane&15, lg = lane>>4;
    int mw = wid>>1, nw = wid&1;
    const short* xb = h_cl + (size_t)b*NPIX*64;
    for(int i=tid; i<1152; i+=256){
        int pix = i>>3, c8 = i&7;
        int hy = pix/12, hx = pix - hy*12;
        int py = ty0 - 2 + hy, px = tx0 - 2 + hx;
        bf16x8 v = {};
        if((unsigned)py < 128u && (unsigned)px < 128u)
            v = *(const bf16x8*)&xb[((size_t)py*128 + px)*64 + c8*8];
        *(bf16x8*)&xt[pix*72 + c8*8] = v;
    }
    __syncthreads();
    f32x4 acc[2] = {};
    for(int q=0; q<25; ++q){
        int ky = q/5, kx = q - ky*5;
        #pragma unroll
        for(int cg=0; cg<2; ++cg){
            bf16x8 av[2];
            #pragma unroll
            for(int mi=0; mi<2; ++mi){
                int m = mw*32 + mi*16 + lr;
                int hp = ((m>>3)+ky)*12 + (m&7)+kx;
                av[mi] = *(const bf16x8*)&xt[hp*72 + cg*32 + lg*8];
            }
            bf16x8 bb = *(const bf16x8*)&wF[((size_t)(25+q)*32 + nw*16 + lr)*64 + cg*32 + lg*8];
            #pragma unroll
            for(int mi=0; mi<2; ++mi) acc[mi] = MFMA(av[mi], bb, acc[mi]);
        }
    }
    int j = nw*16 + lr;
    float bvs = bi[j] + bh[j];
    const float* pF = f1i_all + ((size_t)t*2 + b)*32*NPIX;
    __syncthreads();                        // reuse xt as [64px][40] transpose
    #pragma unroll
    for(int mi=0; mi<2; ++mi){
        int m0 = mw*32 + mi*16 + lg*4;
        int py = ty0 + (m0>>3), px = tx0 + (m0&7);
        f32x4 p = *(const f32x4*)&pF[(size_t)j*NPIX + py*128 + px];
        #pragma unroll
        for(int r=0; r<4; ++r) xt[(m0+r)*40 + j] = f2bf(leakyf(acc[mi][r] + p[r] + bvs));
    }
    __syncthreads();
    {
        int px = tid>>2, c8 = tid&3;
        int pix = (ty0 + (px>>3))*128 + tx0 + (px&7);
        *(bf16x8*)&f1_cl[((size_t)b*NPIX + pix)*32 + c8*8] = *(const bf16x8*)&xt[px*40 + c8*8];
    }
}

// ---- flow: 5x5 p2, 32->26(pad 32), 256 thr, B direct from global ----
__global__ __launch_bounds__(256) void flow_mfma(const short* __restrict__ f1_cl,
        const short* __restrict__ wA, const float* __restrict__ bias, float* __restrict__ flows){
    __shared__ short xt[144*40];
    int bx = blockIdx.x;
    int tile = bx & 255, b = bx>>8;
    int ty0 = (tile>>4)*8, tx0 = (tile&15)*8;
    int tid = threadIdx.x, wid = tid>>6, lane = tid&63, lr = lane&15, lg = lane>>4;
    int mw = wid>>1, nw = wid&1;
    f32x4 acc[2] = {};
    const short* xb = f1_cl + (size_t)b*NPIX*32;
    for(int i=tid; i<576; i+=256){
        int pix = i>>2, c8 = i&3;
        int hy = pix/12, hx = pix - hy*12;
        int py = ty0 - 2 + hy, px = tx0 - 2 + hx;
        bf16x8 v = {};
        if((unsigned)py < 128u && (unsigned)px < 128u)
            v = *(const bf16x8*)&xb[((size_t)py*128 + px)*32 + c8*8];
        *(bf16x8*)&xt[pix*40 + c8*8] = v;
    }
    __syncthreads();
    for(int ky=0; ky<5; ++ky){
        #pragma unroll
        for(int kx=0; kx<5; ++kx){
            bf16x8 av[2];
            #pragma unroll
            for(int mi=0; mi<2; ++mi){
                int m = mw*32 + mi*16 + lr;
                int hp = ((m>>3)+ky)*12 + (m&7) + kx;
                av[mi] = *(const bf16x8*)&xt[hp*40 + lg*8];
            }
            bf16x8 bb = *(const bf16x8*)&wA[((size_t)((ky*5+kx)*32) + nw*16 + lr)*32 + lg*8];
            #pragma unroll
            for(int mi=0; mi<2; ++mi) acc[mi] = MFMA(av[mi], bb, acc[mi]);
        }
    }
    int j = nw*16 + lr;
    if(j < 26){
        float bvs = bias[j];
        #pragma unroll
        for(int mi=0; mi<2; ++mi){
            int m0 = mw*32 + mi*16 + lg*4;
            int py = ty0 + (m0>>3), px = tx0 + (m0&7);
            f32x4 r = acc[mi];
            f32x4 st; st[0]=r[0]+bvs; st[1]=r[1]+bvs; st[2]=r[2]+bvs; st[3]=r[3]+bvs;
            *(f32x4*)&flows[((size_t)b*26 + j)*NPIX + py*128 + px] = st;
        }
    }
}

// ---- warpret: depth-2 software pipeline; LDS dbuf gather + GEMM + fused GRU ----
__device__ __forceinline__ void calc_corners(const float* __restrict__ s_sx,
        const float* __restrict__ s_sy, int l, int mypx,
        int& i00, int& i10, int& i01, int& i11,
        float& w00, float& w10, float& w01, float& w11){
    float sx = s_sx[l*64+mypx], sy = s_sy[l*64+mypx];
    float x0f = floorf(sx), y0f = floorf(sy);
    int x0 = (int)x0f, y0 = (int)y0f;
    float wx1 = sx-x0f, wy1 = sy-y0f, wx0 = 1.f-wx1, wy0 = 1.f-wy1;
    bool vx0 = (unsigned)x0<128u, vx1 = (unsigned)(x0+1)<128u;
    bool vy0 = (unsigned)y0<128u, vy1 = (unsigned)(y0+1)<128u;
    w00 = (vx0&&vy0)? wx0*wy0 : 0.f;
    w10 = (vx1&&vy0)? wx1*wy0 : 0.f;
    w01 = (vx0&&vy1)? wx0*wy1 : 0.f;
    w11 = (vx1&&vy1)? wx1*wy1 : 0.f;
    int xc0 = max(0,min(127,x0)), xc1 = max(0,min(127,x0+1));
    int yc0 = max(0,min(127,y0)), yc1 = max(0,min(127,y0+1));
    i00 = yc0*128+xc0; i10 = yc0*128+xc1; i01 = yc1*128+xc0; i11 = yc1*128+xc1;
}

__global__ __launch_bounds__(256) void warpret_mfma(
        const float* __restrict__ hprev_f32, int hstride,
        const short* __restrict__ h_in,
        const float* __restrict__ flows,
        const short* __restrict__ wret, const float* __restrict__ b_ret,
        const short* __restrict__ ib_bf, float* __restrict__ out,
        short* __restrict__ h_out, int t){
    __shared__ float s_sx[832], s_sy[832];
    __shared__ short At[2][64*40];
    __shared__ short Bt[2][192*40];
    int bx = blockIdx.x;
    int half = bx & 1, row = (bx>>1) & 127, b = bx >> 8;
    int pxbase = half*64;
    int tid = threadIdx.x, wid = tid>>6, lane = tid&63, lr = lane&15, lg = lane>>4;
    const short* hc = h_in + (size_t)b*NPIX*64;
    f32x4 acc[12] = {};
    for(int i=tid; i<832; i+=256){
        int l = i>>6, px = i&63;
        float u = flows[((size_t)b*26 + 2*l)*NPIX + row*128 + pxbase + px];
        float v = flows[((size_t)b*26 + 2*l+1)*NPIX + row*128 + pxbase + px];
        s_sx[i] = (float)(pxbase+px) - u;
        s_sy[i] = (float)row - v;
    }
    __syncthreads();

    int spx = tid & 63, sch = tid >> 6;
    int brow = tid >> 2, bc4 = tid & 3;

    auto issue = [&](int sp, bf16x8& g00, bf16x8& g10, bf16x8& g01, bf16x8& g11,
                     bf16x8& q0, bf16x8& q1, bf16x8& q2,
                     float& w00, float& w10, float& w01, float& w11){
        int i00,i10,i01,i11;
        calc_corners(s_sx, s_sy, sp>>1, spx, i00,i10,i01,i11, w00,w10,w01,w11);
        int cb = (sp&1)*32 + sch*8;
        g00 = *(const bf16x8*)&hc[(size_t)i00*64 + cb];
        g10 = *(const bf16x8*)&hc[(size_t)i10*64 + cb];
        g01 = *(const bf16x8*)&hc[(size_t)i01*64 + cb];
        g11 = *(const bf16x8*)&hc[(size_t)i11*64 + cb];
        q0 = *(const bf16x8*)&wret[((size_t)sp*192 + brow      )*32 + bc4*8];
        q1 = *(const bf16x8*)&wret[((size_t)sp*192 + brow +  64)*32 + bc4*8];
        q2 = *(const bf16x8*)&wret[((size_t)sp*192 + brow + 128)*32 + bc4*8];
    };
    auto commit = [&](int buf, bf16x8 g00, bf16x8 g10, bf16x8 g01, bf16x8 g11,
                      bf16x8 q0, bf16x8 q1, bf16x8 q2,
                      float w00, float w10, float w01, float w11){
        bf16x8 av;
        #pragma unroll
        for(int e=0; e<8; ++e)
            av[e] = f2bf(bf2f(g00[e])*w00 + bf2f(g10[e])*w10 +
                         bf2f(g01[e])*w01 + bf2f(g11[e])*w11);
        *(bf16x8*)&At[buf][spx*40 + sch*8] = av;
        *(bf16x8*)&Bt[buf][(brow      )*40 + bc4*8] = q0;
        *(bf16x8*)&Bt[buf][(brow +  64)*40 + bc4*8] = q1;
        *(bf16x8*)&Bt[buf][(brow + 128)*40 + bc4*8] = q2;
    };

    // prologue: slice 0 -> buf0; pend = slice 1 (in flight across the loop head)
    {
        bf16x8 g00,g10,g01,g11,q0,q1,q2; float w00,w10,w01,w11;
        issue(0, g00,g10,g01,g11,q0,q1,q2, w00,w10,w01,w11);
        commit(0, g00,g10,g01,g11,q0,q1,q2, w00,w10,w01,w11);
    }
    bf16x8 p00,p10,p01,p11,pq0,pq1,pq2; float v00,v10,v01,v11;
    issue(1, p00,p10,p01,p11,pq0,pq1,pq2, v00,v10,v01,v11);
    __syncthreads();

    for(int s=0; s<26; ++s){
        int cur = s & 1, nxt = cur ^ 1;
        bf16x8 n00,n10,n01,n11,nq0,nq1,nq2; float u00,u10,u01,u11;
        if(s < 24)
            issue(s+2, n00,n10,n01,n11,nq0,nq1,nq2, u00,u10,u01,u11);
        {
            bf16x8 a = *(const bf16x8*)&At[cur][(wid*16 + lr)*40 + lg*8];
            #pragma unroll
            for(int ni=0; ni<12; ++ni){
                bf16x8 bb = *(const bf16x8*)&Bt[cur][(ni*16 + lr)*40 + lg*8];
                acc[ni] = MFMA(a, bb, acc[ni]);
            }
        }
        if(s < 25)
            commit(nxt, p00,p10,p01,p11,pq0,pq1,pq2, v00,v10,v01,v11);
        __syncthreads();
        if(s < 24){
            p00=n00; p10=n10; p01=n01; p11=n11;
            pq0=nq0; pq1=nq1; pq2=nq2;
            v00=u00; v10=u10; v01=u01; v11=u11;
        }
    }

    short* Ht = &Bt[0][0];
    const short* ib = ib_bf + (size_t)b*192*NPIX + row*128 + pxbase;
    const float* hbf = hprev_f32 + (size_t)b*hstride + row*128 + pxbase;
    float* ob = out + (((size_t)b*T_ + t)*64)*NPIX + row*128 + pxbase;
    int px4 = wid*16 + lg*4;
    #pragma unroll
    for(int ni=0; ni<4; ++ni){
        int oc = ni*16 + lr;
        bf16x4 irv = *(const bf16x4*)&ib[(size_t)oc*NPIX + px4];
        bf16x4 iuv = *(const bf16x4*)&ib[(size_t)(64+oc)*NPIX + px4];
        bf16x4 imv = *(const bf16x4*)&ib[(size_t)(128+oc)*NPIX + px4];
        f32x4 hp = *(const f32x4*)&hbf[(size_t)oc*NPIX + px4];
        float br = b_ret[oc], bu = b_ret[64+oc], bm = b_ret[128+oc];
        f32x4 st;
        #pragma unroll
        for(int r=0; r<4; ++r){
            float hr = acc[ni][r] + br;
            float hu = acc[ni+4][r] + bu;
            float hm = acc[ni+8][r] + bm;
            float rg = sigmf(bf2f(irv[r]) + hr);
            float zg = sigmf(bf2f(iuv[r]) + hu);
            float mg = leakyf(bf2f(imv[r]) + rg*hm);
            st[r] = zg*hp[r] + (1.f-zg)*mg;
        }
        *(f32x4*)&ob[(size_t)oc*NPIX + px4] = st;
        #pragma unroll
        for(int r=0; r<4; ++r) Ht[(px4+r)*72 + oc] = f2bf(st[r]);
    }
    __syncthreads();
    short* ho = h_out + ((size_t)b*NPIX + row*128 + pxbase)*64;
    for(int i=tid; i<512; i+=256){
        int px = i>>3, c8 = i&7;
        *(bf16x8*)&ho[(size_t)px*64 + c8*8] = *(const bf16x8*)&Ht[px*72 + c8*8];
    }
}

extern "C" void kernel_launch(void* const* d_in, const int* in_sizes, int n_in,
                              void* d_out, int out_size, void* d_ws, size_t ws_size,
                              hipStream_t stream) {
    const float* x      = (const float*)d_in[0];
    const float* w_stem = (const float*)d_in[1];
    const float* b_stem = (const float*)d_in[2];
    const float* w_i2h  = (const float*)d_in[3];
    const float* b_i2h  = (const float*)d_in[4];
    const float* w_i2f  = (const float*)d_in[5];
    const float* b_i2f  = (const float*)d_in[6];
    const float* w_h2f  = (const float*)d_in[7];
    const float* b_h2f  = (const float*)d_in[8];
    const float* w_flow = (const float*)d_in[9];
    const float* b_flow = (const float*)d_in[10];
    const float* w_ret  = (const float*)d_in[11];
    const float* b_ret  = (const float*)d_in[12];
    float* out = (float*)d_out;

    char* w = (char*)d_ws;
    float* h0_f32  = (float*)w;  w += (size_t)2*64*NPIX*4;        // 8.4 MB
    short* i2h_all = (short*)w;  w += (size_t)6*2*192*NPIX*2;     // 75.5 MB (bf16)
    float* f1i_all = (float*)w;  w += (size_t)6*2*32*NPIX*4;      // 25.2 MB
    float* flows   = (float*)w;  w += (size_t)2*26*NPIX*4;        // 3.4 MB
    short* ys_cl   = (short*)w;  w += (size_t)2*NPIX*384*2;       // 25.2 MB
    short* h_clA   = (short*)w;  w += (size_t)2*NPIX*64*2;        // 4.2 MB
    short* h_clB   = (short*)w;  w += (size_t)2*NPIX*64*2;        // 4.2 MB
    short* f1_cl   = (short*)w;  w += (size_t)2*NPIX*32*2;        // 2.1 MB
    short* wAbase  = (short*)w;                                   // 0.9 MB
    short* wA_i2h  = wAbase;
    short* wA_f1   = wAbase + 110592;
    short* wA_flow = wAbase + 212992;
    short* wA_ret  = wAbase + 238592;
    short* wA_stem = wAbase + 398336;

    prep_w<<<1652, 256, 0, stream>>>(w_i2h, w_i2f, w_h2f, w_flow, w_ret, w_stem, wAbase);
    hipMemsetAsync(h0_f32, 0, (size_t)2*64*NPIX*4, stream);
    hipMemsetAsync(h_clA, 0, (size_t)2*NPIX*64*2, stream);

    stem_mfma<<<1024, 256, 0, stream>>>(x, wA_stem, b_stem, ys_cl);
    ih_if_mfma<<<768, 512, 0, stream>>>(ys_cl, wA_i2h, b_i2h, wA_f1, i2h_all, f1i_all);

    for (int t = 0; t < T_; ++t) {
        const float* hprev = (t == 0) ? h0_f32 : out + (size_t)(t - 1) * 64 * NPIX;
        int hstride = (t == 0) ? 64 * NPIX : T_ * 64 * NPIX;
        short* h_in  = (t & 1) ? h_clB : h_clA;
        short* h_nxt = (t & 1) ? h_clA : h_clB;
        f1h_mfma<<<512, 256, 0, stream>>>(h_in, wA_f1, f1i_all, t, b_i2f, b_h2f, f1_cl);
        flow_mfma<<<512, 256, 0, stream>>>(f1_cl, wA_flow, b_flow, flows);
        warpret_mfma<<<512, 256, 0, stream>>>(hprev, hstride, h_in, flows,
                                              wA_ret, b_ret,
                                              i2h_all + (size_t)t*2*192*NPIX,
                                              out, h_nxt, t);
    }
}

// Round 14
// 492.834 us; speedup vs baseline: 1.0633x; 1.0090x over previous
//
#include <hip/hip_runtime.h>
#include <cstddef>

#define NPIX 16384
#define T_ 6

typedef __attribute__((ext_vector_type(8))) short bf16x8;
typedef __attribute__((ext_vector_type(4))) short bf16x4;
typedef __attribute__((ext_vector_type(4))) float f32x4;
typedef __attribute__((ext_vector_type(4))) unsigned u32x4;
typedef __attribute__((ext_vector_type(2))) unsigned u32x2;

__device__ __forceinline__ float leakyf(float x){ return x >= 0.f ? x : 0.2f*x; }
__device__ __forceinline__ float sigmf(float x){ return 1.f/(1.f+__expf(-x)); }
__device__ __forceinline__ short f2bf(float f){
    unsigned u = __float_as_uint(f);
    u += 0x7fffu + ((u>>16)&1u);
    return (short)(u>>16);
}
__device__ __forceinline__ float bf2f(short s){
    return __uint_as_float(((unsigned)(unsigned short)s)<<16);
}
__device__ __forceinline__ unsigned cvtpk(float lo, float hi){
    unsigned d;
    asm("v_cvt_pk_bf16_f32 %0, %1, %2" : "=v"(d) : "v"(lo), "v"(hi));
    return d;
}
__device__ __forceinline__ f32x4 MFMA(bf16x8 a, bf16x8 b, f32x4 c){
    return __builtin_amdgcn_mfma_f32_16x16x32_bf16(a, b, c, 0, 0, 0);
}

// ---- prep: weights -> bf16 [tap][oc][ic] (+ stem im2col [oc][64k]) ----
// wA_i2h [9][192][64] | wA_f1 [50][32][64] | wA_flow [25][32][32] | wA_ret [26][192][32] | wA_stem [384][64]
__global__ __launch_bounds__(256) void prep_w(const float* __restrict__ wi2h,
        const float* __restrict__ wf1i, const float* __restrict__ wf1h,
        const float* __restrict__ wfl, const float* __restrict__ wrt,
        const float* __restrict__ wst, short* __restrict__ dst){
    int idx = blockIdx.x*256 + threadIdx.x;
    float v;
    if(idx < 110592){
        int kk = idx/12288, r = idx%12288, oc = r>>6, ic = r&63;
        v = wi2h[((size_t)(oc*64+ic))*9 + kk];
    } else if(idx < 212992){
        int j = idx-110592; int tap = j>>11, r = j&2047, oc = r>>6, ic = r&63;
        int inp = tap/25, q = tap%25;
        const float* s = inp ? wf1h : wf1i;
        v = s[((size_t)(oc*64+ic))*25 + q];
    } else if(idx < 238592){
        int j = idx-212992; int q = j>>10, r = j&1023, oc = r>>5, ic = r&31;
        v = (oc < 26) ? wfl[((size_t)(oc*32+ic))*25 + q] : 0.f;
    } else if(idx < 398336){
        int j = idx-238592; int s_ = j/6144, r = j%6144, oc = r>>5, c = r&31;
        v = wrt[(size_t)oc*832 + s_*32 + c];
    } else {
        int j = idx-398336; int oc = j>>6, k = j&63;
        if(k < 54){ int ic = k/9, kk = k%9; v = wst[((size_t)(oc*6+ic))*9 + kk]; }
        else v = 0.f;
    }
    dst[idx] = f2bf(v);
}

// ---- stem MFMA: 3x3 s2 p1, 6->384, K=64(54), oc split across 2 blocks ----
__global__ __launch_bounds__(256) void stem_mfma(const float* __restrict__ x,
        const short* __restrict__ wS, const float* __restrict__ bias, short* __restrict__ ys_cl){
    __shared__ float xh[6*17*18];
    int bx = blockIdx.x;
    int ohalf = bx & 1, tile = (bx>>1) & 255, b = bx>>9;
    int ty0 = (tile>>4)*8, tx0 = (tile&15)*8;
    int tid = threadIdx.x, wid = tid>>6, lane = tid&63, lr = lane&15, lg = lane>>4;
    int iy0 = ty0*2-1, ix0 = tx0*2-1;
    for(int i=tid; i<1734; i+=256){
        int ic = i/289, r = i%289, hy = r/17, hx = r%17;
        int iy = iy0+hy, ix = ix0+hx;
        float v = 0.f;
        if((unsigned)iy<256u && (unsigned)ix<256u) v = x[((size_t)b*6+ic)*65536 + iy*256 + ix];
        xh[(ic*17+hy)*18+hx] = v;
    }
    __syncthreads();
    int pxl = wid*16 + lr;
    int ry = (pxl>>3)*2, rx = (pxl&7)*2;
    bf16x8 a[2];
    #pragma unroll
    for(int cg=0; cg<2; ++cg){
        #pragma unroll
        for(int e=0; e<8; ++e){
            int k = cg*32 + lg*8 + e;
            float v = 0.f;
            if(k < 54){
                int ic = k/9, t9 = k%9, ky = t9/3, kx = t9%3;
                v = xh[(ic*17 + ry+ky)*18 + rx+kx];
            }
            a[cg][e] = f2bf(v);
        }
    }
    short* yb = ys_cl + (size_t)b*NPIX*384;
    #pragma unroll
    for(int nj=0; nj<12; ++nj){
        int oc = (ohalf*12 + nj)*16 + lr;
        f32x4 acc = {};
        #pragma unroll
        for(int cg=0; cg<2; ++cg){
            bf16x8 bb = *(const bf16x8*)&wS[(size_t)oc*64 + cg*32 + lg*8];
            acc = MFMA(a[cg], bb, acc);
        }
        float bvs = bias[oc];
        #pragma unroll
        for(int r=0; r<4; ++r){
            int pxr = wid*16 + lg*4 + r;
            int pix = (ty0 + (pxr>>3))*128 + tx0 + (pxr&7);
            yb[(size_t)pix*384 + oc] = f2bf(leakyf(acc[r]+bvs));
        }
    }
}

// ---- fused pre-loop: 8x32 tiles (M=256), 512 thr; i2h (3x3->192, bf16 out) + i2f partial ----
__global__ __launch_bounds__(512) void ih_if_mfma(const short* __restrict__ ys_cl,
        const short* __restrict__ wI, const float* __restrict__ bI,
        const short* __restrict__ wF,
        short* __restrict__ i2h_all, float* __restrict__ f1i_all){
    __shared__ short xt[432*72];            // halo 12 rows x 36 px, 64ch rows (stride 72) = 62 KB
    int bx = blockIdx.x;
    int tile = bx & 63; int r_ = bx >> 6; int t = r_ % 6; int b = r_ / 6;
    int ty0 = (tile>>2)*8, tx0 = (tile&3)*32;
    int tid = threadIdx.x, wid = tid>>6, lane = tid&63, lr = lane&15, lg = lane>>4;
    int mw = wid>>2, nw = wid&3;
    const short* xb = ys_cl + (size_t)b*NPIX*384 + t*64;
    for(int i=tid; i<3456; i+=512){
        int pix = i>>3, c8 = i&7;
        int hy = pix/36, hx = pix - hy*36;
        int py = ty0 - 2 + hy, px = tx0 - 2 + hx;
        bf16x8 v = {};
        if((unsigned)py < 128u && (unsigned)px < 128u)
            v = *(const bf16x8*)&xb[((size_t)py*128 + px)*384 + c8*8];
        *(bf16x8*)&xt[pix*72 + c8*8] = v;
    }
    __syncthreads();
    // ---- i2h: 3x3, this wave: rows mw*4+{0..3}, oc nw*48+{0..47} ----
    f32x4 accI[4][2][3] = {};
    for(int kk=0; kk<9; ++kk){
        int ky = kk/3, kx = kk - ky*3;
        #pragma unroll
        for(int cg=0; cg<2; ++cg){
            bf16x8 bv[3];
            #pragma unroll
            for(int ni=0; ni<3; ++ni)
                bv[ni] = *(const bf16x8*)&wI[((size_t)kk*192 + nw*48 + ni*16 + lr)*64 + cg*32 + lg*8];
            #pragma unroll
            for(int ri=0; ri<4; ++ri){
                int r2 = mw*4 + ri;
                bf16x8 av[2];
                #pragma unroll
                for(int mi=0; mi<2; ++mi){
                    int hp = (r2 + ky + 1)*36 + mi*16 + lr + kx + 1;
                    av[mi] = *(const bf16x8*)&xt[hp*72 + cg*32 + lg*8];
                }
                #pragma unroll
                for(int mi=0; mi<2; ++mi)
                  #pragma unroll
                  for(int ni=0; ni<3; ++ni)
                    accI[ri][mi][ni] = MFMA(av[mi], bv[ni], accI[ri][mi][ni]);
            }
        }
    }
    short* oI = i2h_all + ((size_t)t*2 + b)*192*NPIX;
    #pragma unroll
    for(int ri=0; ri<4; ++ri){
        int py = ty0 + mw*4 + ri;
        #pragma unroll
        for(int mi=0; mi<2; ++mi){
            int px = tx0 + mi*16 + lg*4;
            #pragma unroll
            for(int ni=0; ni<3; ++ni){
                int oc = nw*48 + ni*16 + lr;
                float bvs = bI[oc];
                f32x4 r = accI[ri][mi][ni];
                u32x2 st;
                st[0] = cvtpk(r[0]+bvs, r[1]+bvs);
                st[1] = cvtpk(r[2]+bvs, r[3]+bvs);
                *(u32x2*)&oI[(size_t)oc*NPIX + py*128 + px] = st;
            }
        }
    }
    // ---- i2f: 5x5, partial; this wave: rows mw*4+{0..3}, px-half nw>>1, oc (nw&1)*16+{0..15} ----
    f32x4 accF[4] = {};
    int mif = nw>>1, jF = (nw&1)*16 + lr;
    for(int q=0; q<25; ++q){
        int ky = q/5, kx = q - ky*5;
        #pragma unroll
        for(int cg=0; cg<2; ++cg){
            bf16x8 bb = *(const bf16x8*)&wF[((size_t)q*32 + (nw&1)*16 + lr)*64 + cg*32 + lg*8];
            #pragma unroll
            for(int ri=0; ri<4; ++ri){
                int hp = (mw*4 + ri + ky)*36 + mif*16 + lr + kx;
                bf16x8 av = *(const bf16x8*)&xt[hp*72 + cg*32 + lg*8];
                accF[ri] = MFMA(av, bb, accF[ri]);
            }
        }
    }
    float* oF = f1i_all + ((size_t)t*2 + b)*32*NPIX;
    #pragma unroll
    for(int ri=0; ri<4; ++ri){
        int py = ty0 + mw*4 + ri;
        int px = tx0 + mif*16 + lg*4;
        *(f32x4*)&oF[(size_t)jF*NPIX + py*128 + px] = accF[ri];
    }
}

// ---- f1h (per step): h2f(5x5 on h_cl) + i2f partial + leaky -> f1_cl bf16 ----
__global__ __launch_bounds__(256) void f1h_mfma(const short* __restrict__ h_cl,
        const short* __restrict__ wF, const float* __restrict__ f1i_all, int t,
        const float* __restrict__ bi, const float* __restrict__ bh,
        short* __restrict__ f1_cl){
    __shared__ short xt[144*72];
    int bx = blockIdx.x;
    int tile = bx & 255, b = bx>>8;
    int ty0 = (tile>>4)*8, tx0 = (tile&15)*8;
    int tid = threadIdx.x, wid = tid>>6, lane = tid&63, lr = lane&15, lg = lane>>4;
    int mw = wid>>1, nw = wid&1;
    const short* xb = h_cl + (size_t)b*NPIX*64;
    for(int i=tid; i<1152; i+=256){
        int pix = i>>3, c8 = i&7;
        int hy = pix/12, hx = pix - hy*12;
        int py = ty0 - 2 + hy, px = tx0 - 2 + hx;
        bf16x8 v = {};
        if((unsigned)py < 128u && (unsigned)px < 128u)
            v = *(const bf16x8*)&xb[((size_t)py*128 + px)*64 + c8*8];
        *(bf16x8*)&xt[pix*72 + c8*8] = v;
    }
    __syncthreads();
    f32x4 acc[2] = {};
    for(int q=0; q<25; ++q){
        int ky = q/5, kx = q - ky*5;
        #pragma unroll
        for(int cg=0; cg<2; ++cg){
            bf16x8 av[2];
            #pragma unroll
            for(int mi=0; mi<2; ++mi){
                int m = mw*32 + mi*16 + lr;
                int hp = ((m>>3)+ky)*12 + (m&7)+kx;
                av[mi] = *(const bf16x8*)&xt[hp*72 + cg*32 + lg*8];
            }
            bf16x8 bb = *(const bf16x8*)&wF[((size_t)(25+q)*32 + nw*16 + lr)*64 + cg*32 + lg*8];
            #pragma unroll
            for(int mi=0; mi<2; ++mi) acc[mi] = MFMA(av[mi], bb, acc[mi]);
        }
    }
    int j = nw*16 + lr;
    float bvs = bi[j] + bh[j];
    const float* pF = f1i_all + ((size_t)t*2 + b)*32*NPIX;
    __syncthreads();                        // reuse xt as [64px][40] transpose
    #pragma unroll
    for(int mi=0; mi<2; ++mi){
        int m0 = mw*32 + mi*16 + lg*4;
        int py = ty0 + (m0>>3), px = tx0 + (m0&7);
        f32x4 p = *(const f32x4*)&pF[(size_t)j*NPIX + py*128 + px];
        #pragma unroll
        for(int r=0; r<4; ++r) xt[(m0+r)*40 + j] = f2bf(leakyf(acc[mi][r] + p[r] + bvs));
    }
    __syncthreads();
    {
        int px = tid>>2, c8 = tid&3;
        int pix = (ty0 + (px>>3))*128 + tx0 + (px&7);
        *(bf16x8*)&f1_cl[((size_t)b*NPIX + pix)*32 + c8*8] = *(const bf16x8*)&xt[px*40 + c8*8];
    }
}

// ---- flow: 5x5 p2, 32->26(pad 32), 256 thr, B direct from global ----
__global__ __launch_bounds__(256) void flow_mfma(const short* __restrict__ f1_cl,
        const short* __restrict__ wA, const float* __restrict__ bias, float* __restrict__ flows){
    __shared__ short xt[144*40];
    int bx = blockIdx.x;
    int tile = bx & 255, b = bx>>8;
    int ty0 = (tile>>4)*8, tx0 = (tile&15)*8;
    int tid = threadIdx.x, wid = tid>>6, lane = tid&63, lr = lane&15, lg = lane>>4;
    int mw = wid>>1, nw = wid&1;
    f32x4 acc[2] = {};
    const short* xb = f1_cl + (size_t)b*NPIX*32;
    for(int i=tid; i<576; i+=256){
        int pix = i>>2, c8 = i&3;
        int hy = pix/12, hx = pix - hy*12;
        int py = ty0 - 2 + hy, px = tx0 - 2 + hx;
        bf16x8 v = {};
        if((unsigned)py < 128u && (unsigned)px < 128u)
            v = *(const bf16x8*)&xb[((size_t)py*128 + px)*32 + c8*8];
        *(bf16x8*)&xt[pix*40 + c8*8] = v;
    }
    __syncthreads();
    for(int ky=0; ky<5; ++ky){
        #pragma unroll
        for(int kx=0; kx<5; ++kx){
            bf16x8 av[2];
            #pragma unroll
            for(int mi=0; mi<2; ++mi){
                int m = mw*32 + mi*16 + lr;
                int hp = ((m>>3)+ky)*12 + (m&7) + kx;
                av[mi] = *(const bf16x8*)&xt[hp*40 + lg*8];
            }
            bf16x8 bb = *(const bf16x8*)&wA[((size_t)((ky*5+kx)*32) + nw*16 + lr)*32 + lg*8];
            #pragma unroll
            for(int mi=0; mi<2; ++mi) acc[mi] = MFMA(av[mi], bb, acc[mi]);
        }
    }
    int j = nw*16 + lr;
    if(j < 26){
        float bvs = bias[j];
        #pragma unroll
        for(int mi=0; mi<2; ++mi){
            int m0 = mw*32 + mi*16 + lg*4;
            int py = ty0 + (m0>>3), px = tx0 + (m0&7);
            f32x4 r = acc[mi];
            f32x4 st; st[0]=r[0]+bvs; st[1]=r[1]+bvs; st[2]=r[2]+bvs; st[3]=r[3]+bvs;
            *(f32x4*)&flows[((size_t)b*26 + j)*NPIX + py*128 + px] = st;
        }
    }
}

// ---- warpret: depth-2 software pipeline; LDS dbuf gather + GEMM + fused GRU ----
__device__ __forceinline__ void calc_corners(const float* __restrict__ s_sx,
        const float* __restrict__ s_sy, int l, int mypx,
        int& i00, int& i10, int& i01, int& i11,
        float& w00, float& w10, float& w01, float& w11){
    float sx = s_sx[l*64+mypx], sy = s_sy[l*64+mypx];
    float x0f = floorf(sx), y0f = floorf(sy);
    int x0 = (int)x0f, y0 = (int)y0f;
    float wx1 = sx-x0f, wy1 = sy-y0f, wx0 = 1.f-wx1, wy0 = 1.f-wy1;
    bool vx0 = (unsigned)x0<128u, vx1 = (unsigned)(x0+1)<128u;
    bool vy0 = (unsigned)y0<128u, vy1 = (unsigned)(y0+1)<128u;
    w00 = (vx0&&vy0)? wx0*wy0 : 0.f;
    w10 = (vx1&&vy0)? wx1*wy0 : 0.f;
    w01 = (vx0&&vy1)? wx0*wy1 : 0.f;
    w11 = (vx1&&vy1)? wx1*wy1 : 0.f;
    int xc0 = max(0,min(127,x0)), xc1 = max(0,min(127,x0+1));
    int yc0 = max(0,min(127,y0)), yc1 = max(0,min(127,y0+1));
    i00 = yc0*128+xc0; i10 = yc0*128+xc1; i01 = yc1*128+xc0; i11 = yc1*128+xc1;
}

__global__ __launch_bounds__(256) void warpret_mfma(
        const float* __restrict__ hprev_f32, int hstride,
        const short* __restrict__ h_in,
        const float* __restrict__ flows,
        const short* __restrict__ wret, const float* __restrict__ b_ret,
        const short* __restrict__ ib_bf, float* __restrict__ out,
        short* __restrict__ h_out, int t){
    __shared__ float s_sx[832], s_sy[832];
    __shared__ short At[2][64*40];
    __shared__ short Bt[2][192*40];
    int bx = blockIdx.x;
    int half = bx & 1, row = (bx>>1) & 127, b = bx >> 8;
    int pxbase = half*64;
    int tid = threadIdx.x, wid = tid>>6, lane = tid&63, lr = lane&15, lg = lane>>4;
    const short* hc = h_in + (size_t)b*NPIX*64;
    f32x4 acc[12] = {};
    for(int i=tid; i<832; i+=256){
        int l = i>>6, px = i&63;
        float u = flows[((size_t)b*26 + 2*l)*NPIX + row*128 + pxbase + px];
        float v = flows[((size_t)b*26 + 2*l+1)*NPIX + row*128 + pxbase + px];
        s_sx[i] = (float)(pxbase+px) - u;
        s_sy[i] = (float)row - v;
    }
    __syncthreads();

    int spx = tid & 63, sch = tid >> 6;
    int brow = tid >> 2, bc4 = tid & 3;

    auto issue = [&](int sp, bf16x8& g00, bf16x8& g10, bf16x8& g01, bf16x8& g11,
                     bf16x8& q0, bf16x8& q1, bf16x8& q2,
                     float& w00, float& w10, float& w01, float& w11){
        int i00,i10,i01,i11;
        calc_corners(s_sx, s_sy, sp>>1, spx, i00,i10,i01,i11, w00,w10,w01,w11);
        int cb = (sp&1)*32 + sch*8;
        g00 = *(const bf16x8*)&hc[(size_t)i00*64 + cb];
        g10 = *(const bf16x8*)&hc[(size_t)i10*64 + cb];
        g01 = *(const bf16x8*)&hc[(size_t)i01*64 + cb];
        g11 = *(const bf16x8*)&hc[(size_t)i11*64 + cb];
        q0 = *(const bf16x8*)&wret[((size_t)sp*192 + brow      )*32 + bc4*8];
        q1 = *(const bf16x8*)&wret[((size_t)sp*192 + brow +  64)*32 + bc4*8];
        q2 = *(const bf16x8*)&wret[((size_t)sp*192 + brow + 128)*32 + bc4*8];
    };
    auto commit = [&](int buf, bf16x8 g00, bf16x8 g10, bf16x8 g01, bf16x8 g11,
                      bf16x8 q0, bf16x8 q1, bf16x8 q2,
                      float w00, float w10, float w01, float w11){
        float r[8];
        #pragma unroll
        for(int e=0; e<8; ++e)
            r[e] = bf2f(g00[e])*w00 + bf2f(g10[e])*w10 +
                   bf2f(g01[e])*w01 + bf2f(g11[e])*w11;
        u32x4 av;
        av[0] = cvtpk(r[0], r[1]);
        av[1] = cvtpk(r[2], r[3]);
        av[2] = cvtpk(r[4], r[5]);
        av[3] = cvtpk(r[6], r[7]);
        *(u32x4*)&At[buf][spx*40 + sch*8] = av;
        *(bf16x8*)&Bt[buf][(brow      )*40 + bc4*8] = q0;
        *(bf16x8*)&Bt[buf][(brow +  64)*40 + bc4*8] = q1;
        *(bf16x8*)&Bt[buf][(brow + 128)*40 + bc4*8] = q2;
    };

    // prologue: slice 0 -> buf0; pend = slice 1 (in flight across the loop head)
    {
        bf16x8 g00,g10,g01,g11,q0,q1,q2; float w00,w10,w01,w11;
        issue(0, g00,g10,g01,g11,q0,q1,q2, w00,w10,w01,w11);
        commit(0, g00,g10,g01,g11,q0,q1,q2, w00,w10,w01,w11);
    }
    bf16x8 p00,p10,p01,p11,pq0,pq1,pq2; float v00,v10,v01,v11;
    issue(1, p00,p10,p01,p11,pq0,pq1,pq2, v00,v10,v01,v11);
    __syncthreads();

    for(int s=0; s<26; ++s){
        int cur = s & 1, nxt = cur ^ 1;
        bf16x8 n00,n10,n01,n11,nq0,nq1,nq2; float u00,u10,u01,u11;
        if(s < 24)
            issue(s+2, n00,n10,n01,n11,nq0,nq1,nq2, u00,u10,u01,u11);
        {
            bf16x8 a = *(const bf16x8*)&At[cur][(wid*16 + lr)*40 + lg*8];
            #pragma unroll
            for(int ni=0; ni<12; ++ni){
                bf16x8 bb = *(const bf16x8*)&Bt[cur][(ni*16 + lr)*40 + lg*8];
                acc[ni] = MFMA(a, bb, acc[ni]);
            }
        }
        if(s < 25)
            commit(nxt, p00,p10,p01,p11,pq0,pq1,pq2, v00,v10,v01,v11);
        __syncthreads();
        if(s < 24){
            p00=n00; p10=n10; p01=n01; p11=n11;
            pq0=nq0; pq1=nq1; pq2=nq2;
            v00=u00; v10=u10; v01=u01; v11=u11;
        }
    }

    short* Ht = &Bt[0][0];
    const short* ib = ib_bf + (size_t)b*192*NPIX + row*128 + pxbase;
    const float* hbf = hprev_f32 + (size_t)b*hstride + row*128 + pxbase;
    float* ob = out + (((size_t)b*T_ + t)*64)*NPIX + row*128 + pxbase;
    int px4 = wid*16 + lg*4;
    #pragma unroll
    for(int ni=0; ni<4; ++ni){
        int oc = ni*16 + lr;
        bf16x4 irv = *(const bf16x4*)&ib[(size_t)oc*NPIX + px4];
        bf16x4 iuv = *(const bf16x4*)&ib[(size_t)(64+oc)*NPIX + px4];
        bf16x4 imv = *(const bf16x4*)&ib[(size_t)(128+oc)*NPIX + px4];
        f32x4 hp = *(const f32x4*)&hbf[(size_t)oc*NPIX + px4];
        float br = b_ret[oc], bu = b_ret[64+oc], bm = b_ret[128+oc];
        f32x4 st;
        #pragma unroll
        for(int r=0; r<4; ++r){
            float hr = acc[ni][r] + br;
            float hu = acc[ni+4][r] + bu;
            float hm = acc[ni+8][r] + bm;
            float rg = sigmf(bf2f(irv[r]) + hr);
            float zg = sigmf(bf2f(iuv[r]) + hu);
            float mg = leakyf(bf2f(imv[r]) + rg*hm);
            st[r] = zg*hp[r] + (1.f-zg)*mg;
        }
        *(f32x4*)&ob[(size_t)oc*NPIX + px4] = st;
        #pragma unroll
        for(int r=0; r<4; ++r) Ht[(px4+r)*72 + oc] = f2bf(st[r]);
    }
    __syncthreads();
    short* ho = h_out + ((size_t)b*NPIX + row*128 + pxbase)*64;
    for(int i=tid; i<512; i+=256){
        int px = i>>3, c8 = i&7;
        *(bf16x8*)&ho[(size_t)px*64 + c8*8] = *(const bf16x8*)&Ht[px*72 + c8*8];
    }
}

extern "C" void kernel_launch(void* const* d_in, const int* in_sizes, int n_in,
                              void* d_out, int out_size, void* d_ws, size_t ws_size,
                              hipStream_t stream) {
    const float* x      = (const float*)d_in[0];
    const float* w_stem = (const float*)d_in[1];
    const float* b_stem = (const float*)d_in[2];
    const float* w_i2h  = (const float*)d_in[3];
    const float* b_i2h  = (const float*)d_in[4];
    const float* w_i2f  = (const float*)d_in[5];
    const float* b_i2f  = (const float*)d_in[6];
    const float* w_h2f  = (const float*)d_in[7];
    const float* b_h2f  = (const float*)d_in[8];
    const float* w_flow = (const float*)d_in[9];
    const float* b_flow = (const float*)d_in[10];
    const float* w_ret  = (const float*)d_in[11];
    const float* b_ret  = (const float*)d_in[12];
    float* out = (float*)d_out;

    char* w = (char*)d_ws;
    float* h0_f32  = (float*)w;  w += (size_t)2*64*NPIX*4;        // 8.4 MB
    short* i2h_all = (short*)w;  w += (size_t)6*2*192*NPIX*2;     // 75.5 MB (bf16)
    float* f1i_all = (float*)w;  w += (size_t)6*2*32*NPIX*4;      // 25.2 MB
    float* flows   = (float*)w;  w += (size_t)2*26*NPIX*4;        // 3.4 MB
    short* ys_cl   = (short*)w;  w += (size_t)2*NPIX*384*2;       // 25.2 MB
    short* h_clA   = (short*)w;  w += (size_t)2*NPIX*64*2;        // 4.2 MB
    short* h_clB   = (short*)w;  w += (size_t)2*NPIX*64*2;        // 4.2 MB
    short* f1_cl   = (short*)w;  w += (size_t)2*NPIX*32*2;        // 2.1 MB
    short* wAbase  = (short*)w;                                   // 0.9 MB
    short* wA_i2h  = wAbase;
    short* wA_f1   = wAbase + 110592;
    short* wA_flow = wAbase + 212992;
    short* wA_ret  = wAbase + 238592;
    short* wA_stem = wAbase + 398336;

    prep_w<<<1652, 256, 0, stream>>>(w_i2h, w_i2f, w_h2f, w_flow, w_ret, w_stem, wAbase);
    hipMemsetAsync(h0_f32, 0, (size_t)2*64*NPIX*4, stream);
    hipMemsetAsync(h_clA, 0, (size_t)2*NPIX*64*2, stream);

    stem_mfma<<<1024, 256, 0, stream>>>(x, wA_stem, b_stem, ys_cl);
    ih_if_mfma<<<768, 512, 0, stream>>>(ys_cl, wA_i2h, b_i2h, wA_f1, i2h_all, f1i_all);

    for (int t = 0; t < T_; ++t) {
        const float* hprev = (t == 0) ? h0_f32 : out + (size_t)(t - 1) * 64 * NPIX;
        int hstride = (t == 0) ? 64 * NPIX : T_ * 64 * NPIX;
        short* h_in  = (t & 1) ? h_clB : h_clA;
        short* h_nxt = (t & 1) ? h_clA : h_clB;
        f1h_mfma<<<512, 256, 0, stream>>>(h_in, wA_f1, f1i_all, t, b_i2f, b_h2f, f1_cl);
        flow_mfma<<<512, 256, 0, stream>>>(f1_cl, wA_flow, b_flow, flows);
        warpret_mfma<<<512, 256, 0, stream>>>(hprev, hstride, h_in, flows,
                                              wA_ret, b_ret,
                                              i2h_all + (size_t)t*2*192*NPIX,
                                              out, h_nxt, t);
    }
}